// Round 6
// baseline (676.563 us; speedup 1.0000x reference)
//
#include <hip/hip_runtime.h>

#define NSLOTS 2048
#define DIM    512

typedef __bf16 bf16x8 __attribute__((ext_vector_type(8)));
typedef float  f32x4  __attribute__((ext_vector_type(4)));
typedef unsigned short us4 __attribute__((ext_vector_type(4)));
typedef unsigned short us8 __attribute__((ext_vector_type(8)));

typedef const __attribute__((address_space(1))) unsigned* gp_t;
typedef __attribute__((address_space(3))) unsigned* sp_t;

__device__ __forceinline__ void gl16(const void* g, void* l) {
    __builtin_amdgcn_global_load_lds((gp_t)g, (sp_t)l, 16, 0, 0);
}

__device__ __forceinline__ unsigned short f2bf(float f) {
    unsigned u = __builtin_bit_cast(unsigned, f);
    u = (u + 0x7FFFu + ((u >> 16) & 1u)) >> 16;   // RNE
    return (unsigned short)u;
}
__device__ __forceinline__ float bf2f(unsigned short u) {
    unsigned v = ((unsigned)u) << 16;
    return __builtin_bit_cast(float, v);
}

// prep: memN = L2-normalized memory [2048][512] bf16 (row-major);
//       memT = raw memory transposed [512][2048] bf16 (row-major).
__global__ __launch_bounds__(512) void prep_kernel(const float* __restrict__ mem,
                                                   unsigned short* __restrict__ memN,
                                                   unsigned short* __restrict__ memT) {
    __shared__ unsigned short T[32][516];
    const int tid = threadIdx.x;
    const int sl  = tid >> 4;
    const int c16 = tid & 15;
    const int n   = blockIdx.x * 32 + sl;
    const f32x4* row = (const f32x4*)(mem + (size_t)n * DIM);
    f32x4 v[8];
    float s = 0.f;
    #pragma unroll
    for (int j = 0; j < 8; ++j) {
        v[j] = row[c16*8 + j];
        s += v[j][0]*v[j][0] + v[j][1]*v[j][1] + v[j][2]*v[j][2] + v[j][3]*v[j][3];
    }
    #pragma unroll
    for (int off = 1; off < 16; off <<= 1) s += __shfl_xor(s, off);
    const float rn = 1.0f / fmaxf(sqrtf(s), 1e-12f);
    #pragma unroll
    for (int j = 0; j < 8; ++j) {
        us4 p, q;
        #pragma unroll
        for (int e = 0; e < 4; ++e) { p[e] = f2bf(v[j][e] * rn); q[e] = f2bf(v[j][e]); }
        *(us4*)(memN + (size_t)n * DIM + c16*32 + j*4) = p;
        *(us4*)(&T[sl][c16*32 + j*4]) = q;
    }
    __syncthreads();
    {
        const int c4 = tid & 3;
        #pragma unroll
        for (int i = 0; i < 4; ++i) {
            const int dd = i*128 + (tid >> 2);
            us8 g;
            #pragma unroll
            for (int j = 0; j < 8; ++j) g[j] = T[c4*8 + j][dd];
            *(us8*)(memT + (size_t)dd * NSLOTS + blockIdx.x*32 + c4*8) = g;
        }
    }
}

// K1: z-normalize (fused) + GEMM1 + exp + row sums. 1024 WGs x 512 thr (8 waves 2M x 4N).
// A [64r][512k] persistent in LDS; B dbuf 256-slot chunks, BK=64; 16 MFMA/wave/phase.
// Writes bf16 P=exp(S) to attn-row upper halves (+4096), row sums to ws.
__global__ __launch_bounds__(512) void k1_kernel(const float* __restrict__ z,
                                                 const unsigned short* __restrict__ memN,
                                                 float* attnB,
                                                 float* __restrict__ sums) {
    __shared__ char As[65536];        // [64 r][512 k] bf16, row 1024B, XOR-swizzled
    __shared__ char Bs[2][32768];     // [256 s][64 k] bf16, row 128B, XOR-swizzled
    __shared__ float wsums[4][64];
    const int tid  = threadIdx.x;
    const int wid  = tid >> 6;
    const int lane = tid & 63;
    const int l16  = lane & 15;
    const int l4   = lane >> 4;
    const int m    = wid >> 2, n = wid & 3;
    const size_t rowbase = (size_t)blockIdx.x * 64;

    // ---- phase 0: z -> L2-normalized bf16 A tile in LDS ----
    {
        const int r = tid >> 3, c8 = tid & 7;
        const f32x4* zr = (const f32x4*)(z + (rowbase + r) * DIM);
        f32x4 v[16];
        float s = 0.f;
        #pragma unroll
        for (int j = 0; j < 16; ++j) {
            v[j] = __builtin_nontemporal_load(zr + c8 + j*8);
            s += v[j][0]*v[j][0] + v[j][1]*v[j][1] + v[j][2]*v[j][2] + v[j][3]*v[j][3];
        }
        s += __shfl_xor(s, 1); s += __shfl_xor(s, 2); s += __shfl_xor(s, 4);
        const float rn = 1.0f / fmaxf(sqrtf(s), 1e-12f);
        char* arow = As + r*1024;
        #pragma unroll
        for (int j = 0; j < 16; ++j) {
            us4 p;
            #pragma unroll
            for (int e = 0; e < 4; ++e) p[e] = f2bf(v[j][e] * rn);
            *(us4*)(arow + ((c8*8 + j*64) ^ ((r & 7) << 4))) = p;
        }
    }

    auto stageB = [&](int buf, int t) {
        const int c = t >> 3, ks = t & 7;
        #pragma unroll
        for (int i = 0; i < 4; ++i) {   // 32KB = 2048 x 16B
            const int f = (i*8 + wid)*64 + lane, br = f >> 3, g = f & 7;
            const char* src = (const char*)memN + (size_t)(c*256 + br) * 1024 + ks*128
                            + ((g*16) ^ ((br & 7) << 4));
            gl16(src, &Bs[buf][(i*8 + wid)*1024]);
        }
    };

    const f32x4 zeroV = {0.f, 0.f, 0.f, 0.f};
    f32x4 acc[2][4];
    #pragma unroll
    for (int mt = 0; mt < 2; ++mt)
        #pragma unroll
        for (int nt = 0; nt < 4; ++nt) acc[mt][nt] = zeroV;
    float psum[2][4];
    #pragma unroll
    for (int mt = 0; mt < 2; ++mt)
        #pragma unroll
        for (int r = 0; r < 4; ++r) psum[mt][r] = 0.f;

    stageB(0, 0);
    __syncthreads();

    for (int t = 0; t < 64; ++t) {
        const int c = t >> 3, ks = t & 7;
        if (t < 63) stageB((t + 1) & 1, t + 1);
        const char* Bb = (const char*)&Bs[t & 1][0];
        #pragma unroll
        for (int kk = 0; kk < 2; ++kk) {
            bf16x8 af[2];
            #pragma unroll
            for (int mt = 0; mt < 2; ++mt) {
                const int ar = m*32 + mt*16 + l16;
                af[mt] = *(const bf16x8*)(As + ar*1024 + ((ks*128 + kk*64 + l4*16) ^ ((ar & 7) << 4)));
            }
            #pragma unroll
            for (int nt = 0; nt < 4; ++nt) {
                const int br = n*64 + nt*16 + l16;
                bf16x8 b = *(const bf16x8*)(Bb + br*128 + ((kk*64 + l4*16) ^ ((br & 7) << 4)));
                acc[0][nt] = __builtin_amdgcn_mfma_f32_16x16x32_bf16(af[0], b, acc[0][nt], 0, 0, 0);
                acc[1][nt] = __builtin_amdgcn_mfma_f32_16x16x32_bf16(af[1], b, acc[1][nt], 0, 0, 0);
            }
        }
        __syncthreads();
        if (ks == 7) {
            // exp + psum + pack P chunk [64 r][256 s] bf16 into stale B buffer
            char* Pl = (char*)&Bs[t & 1][0];
            #pragma unroll
            for (int mt = 0; mt < 2; ++mt)
                #pragma unroll
                for (int nt = 0; nt < 4; ++nt)
                    #pragma unroll
                    for (int r = 0; r < 4; ++r) {
                        const float e = __expf(acc[mt][nt][r]);
                        psum[mt][r] += e;
                        const int row = m*32 + mt*16 + l4*4 + r;
                        const int sl  = n*64 + nt*16 + l16;
                        *(unsigned short*)(Pl + row*512 + (((sl >> 3) * 16) ^ ((row & 7) << 4)) + (sl & 7)*2) = f2bf(e);
                        acc[mt][nt][r] = 0.f;
                    }
            __syncthreads();
            {   // bounce out: coalesced NT stores to attn upper halves
                const int prow = tid >> 3, g8 = tid & 7;
                char* gdst = (char*)attnB + (rowbase + prow) * 8192 + 4096 + c*512;
                #pragma unroll
                for (int h = 0; h < 4; ++h) {
                    us8 pv = *(const us8*)(Pl + prow*512 + (((g8 + h*8)*16) ^ ((prow & 7) << 4)));
                    __builtin_nontemporal_store(pv, (us8*)(gdst + (g8 + h*8)*16));
                }
            }
            __syncthreads();
        }
    }

    // row sums
    #pragma unroll
    for (int mt = 0; mt < 2; ++mt)
        #pragma unroll
        for (int r = 0; r < 4; ++r) {
            #pragma unroll
            for (int off = 1; off < 16; off <<= 1) psum[mt][r] += __shfl_xor(psum[mt][r], off);
        }
    if (l16 == 0) {
        #pragma unroll
        for (int mt = 0; mt < 2; ++mt)
            #pragma unroll
            for (int r = 0; r < 4; ++r)
                wsums[n][m*32 + mt*16 + l4*4 + r] = psum[mt][r];
    }
    __syncthreads();
    if (tid < 64) sums[rowbase + tid] = wsums[0][tid] + wsums[1][tid] + wsums[2][tid] + wsums[3][tid];
}

// K2: GEMM2 + normalized attn writes. 1024 WGs x 512 thr (8 waves 2M x 4N).
// ks2 outer (16 slot-chunks of 128), nb inner (4 dim-blocks of 128); 16 MFMA/wave/phase.
__global__ __launch_bounds__(512) void k2_kernel(const unsigned short* __restrict__ memT,
                                                 const float* __restrict__ sums,
                                                 float* __restrict__ zhat,
                                                 float* attnB) {
    __shared__ char ab[2][16384];     // A [64 r][128 s] bf16, row 256B
    __shared__ char bb[2][32768];     // B [128 d][128 s] bf16, row 256B
    __shared__ float rsums[64];
    const int tid  = threadIdx.x;
    const int wid  = tid >> 6;
    const int lane = tid & 63;
    const int l16  = lane & 15;
    const int l4   = lane >> 4;
    const int m    = wid >> 2, n = wid & 3;
    const size_t rowbase = (size_t)blockIdx.x * 64;
    const char* attnRd = (const char*)attnB;

    auto stageA = [&](int buf, int ks2) {
        #pragma unroll
        for (int i = 0; i < 2; ++i) {   // 16KB = 1024 x 16B
            const int f = (i*8 + wid)*64 + lane, ar = f >> 4, g = f & 15;
            const char* src = attnRd + (rowbase + ar) * 8192 + 4096 + ks2*256
                            + ((g*16) ^ ((ar & 7) << 4));
            gl16(src, &ab[buf][(i*8 + wid)*1024]);
        }
    };
    auto stageB = [&](int buf, int ks2, int nb) {
        #pragma unroll
        for (int i = 0; i < 4; ++i) {   // 32KB = 2048 x 16B
            const int f = (i*8 + wid)*64 + lane, dr = f >> 4, g = f & 15;
            const char* src = (const char*)memT + (size_t)(nb*128 + dr) * 4096 + ks2*256
                            + ((g*16) ^ ((dr & 7) << 4));
            gl16(src, &bb[buf][(i*8 + wid)*1024]);
        }
    };

    if (tid < 64) rsums[tid] = 1.0f / sums[rowbase + tid];

    const f32x4 zeroV = {0.f, 0.f, 0.f, 0.f};
    f32x4 acc[4][2][2];
    #pragma unroll
    for (int nb = 0; nb < 4; ++nb)
        #pragma unroll
        for (int mt = 0; mt < 2; ++mt)
            #pragma unroll
            for (int nt = 0; nt < 2; ++nt) acc[nb][mt][nt] = zeroV;

    stageA(0, 0);
    stageB(0, 0, 0);
    __syncthreads();

    for (int ks2 = 0; ks2 < 16; ++ks2) {
        #pragma unroll
        for (int nb = 0; nb < 4; ++nb) {
            const int u = ks2*4 + nb;
            if (nb < 3) stageB((u + 1) & 1, ks2, nb + 1);
            else if (ks2 < 15) { stageA((ks2 + 1) & 1, ks2 + 1); stageB((u + 1) & 1, ks2 + 1, 0); }
            const char* Ab = (const char*)&ab[ks2 & 1][0];
            const char* Bb = (const char*)&bb[u & 1][0];
            if (nb == 0) {   // normalized fp32 attn write for chunk ks2 from staged P
                const int prow = tid >> 3, g8 = tid & 7;
                const float sc = rsums[prow];
                float* dst = attnB + (rowbase + prow) * NSLOTS + ks2*128 + g8*8;
                #pragma unroll
                for (int h = 0; h < 2; ++h) {
                    us8 pv = *(const us8*)(Ab + prow*256 + (((g8 + h*8)*16) ^ ((prow & 7) << 4)));
                    f32x4 o0, o1;
                    #pragma unroll
                    for (int e = 0; e < 4; ++e) { o0[e] = bf2f(pv[e]) * sc; o1[e] = bf2f(pv[e + 4]) * sc; }
                    __builtin_nontemporal_store(o0, (f32x4*)(dst + h*64));
                    __builtin_nontemporal_store(o1, (f32x4*)(dst + h*64 + 4));
                }
            }
            #pragma unroll
            for (int kk = 0; kk < 4; ++kk) {
                bf16x8 af[2];
                #pragma unroll
                for (int mt = 0; mt < 2; ++mt) {
                    const int ar = m*32 + mt*16 + l16;
                    af[mt] = *(const bf16x8*)(Ab + ar*256 + ((kk*64 + l4*16) ^ ((ar & 7) << 4)));
                }
                #pragma unroll
                for (int nt = 0; nt < 2; ++nt) {
                    const int dr = n*32 + nt*16 + l16;
                    bf16x8 b = *(const bf16x8*)(Bb + dr*256 + ((kk*64 + l4*16) ^ ((dr & 7) << 4)));
                    acc[nb][0][nt] = __builtin_amdgcn_mfma_f32_16x16x32_bf16(af[0], b, acc[nb][0][nt], 0, 0, 0);
                    acc[nb][1][nt] = __builtin_amdgcn_mfma_f32_16x16x32_bf16(af[1], b, acc[nb][1][nt], 0, 0, 0);
                }
            }
            __syncthreads();
        }
    }

    // epilogue: zhat
    #pragma unroll
    for (int nb = 0; nb < 4; ++nb)
        #pragma unroll
        for (int mt = 0; mt < 2; ++mt)
            #pragma unroll
            for (int r = 0; r < 4; ++r) {
                const int row = m*32 + mt*16 + l4*4 + r;
                const float rs = rsums[row];
                float* zr = zhat + (rowbase + row) * DIM + nb*128 + n*32 + l16;
                __builtin_nontemporal_store(acc[nb][mt][0][r] * rs, zr);
                __builtin_nontemporal_store(acc[nb][mt][1][r] * rs, zr + 16);
            }
}

extern "C" void kernel_launch(void* const* d_in, const int* in_sizes, int n_in,
                              void* d_out, int out_size, void* d_ws, size_t ws_size,
                              hipStream_t stream) {
    const float* zin = (const float*)d_in[0];
    const float* mem = (const float*)d_in[1];
    const int B = in_sizes[0] / DIM;                       // 65536
    unsigned short* memN = (unsigned short*)d_ws;          // 2 MB
    unsigned short* memT = memN + (size_t)NSLOTS * DIM;    // 2 MB
    float* sums = (float*)(memT + (size_t)NSLOTS * DIM);   // 256 KB
    float* zhat = (float*)d_out;
    float* attn = zhat + (size_t)B * DIM;
    prep_kernel<<<NSLOTS / 32, 512, 0, stream>>>(mem, memN, memT);
    k1_kernel<<<B / 64, 512, 0, stream>>>(zin, memN, attn, sums);
    k2_kernel<<<B / 64, 512, 0, stream>>>(memT, sums, zhat, attn);
}

// Round 7
// 490.935 us; speedup vs baseline: 1.3781x; 1.3781x over previous
//
#include <hip/hip_runtime.h>

#define NSLOTS 2048
#define DIM    512

typedef __bf16 bf16x8 __attribute__((ext_vector_type(8)));
typedef float  f32x4  __attribute__((ext_vector_type(4)));
typedef unsigned short us4 __attribute__((ext_vector_type(4)));
typedef unsigned short us8 __attribute__((ext_vector_type(8)));

typedef const __attribute__((address_space(1))) unsigned* gp_t;
typedef __attribute__((address_space(3))) unsigned* sp_t;

__device__ __forceinline__ void gl16(const void* g, void* l) {
    __builtin_amdgcn_global_load_lds((gp_t)g, (sp_t)l, 16, 0, 0);
}

__device__ __forceinline__ unsigned short f2bf(float f) {
    unsigned u = __builtin_bit_cast(unsigned, f);
    u = (u + 0x7FFFu + ((u >> 16) & 1u)) >> 16;   // RNE
    return (unsigned short)u;
}
__device__ __forceinline__ float bf2f(unsigned short u) {
    unsigned v = ((unsigned)u) << 16;
    return __builtin_bit_cast(float, v);
}

// prep: memN = L2-normalized memory [2048][512] bf16; memT = raw memory transposed [512][2048] bf16.
__global__ __launch_bounds__(512) void prep_kernel(const float* __restrict__ mem,
                                                   unsigned short* __restrict__ memN,
                                                   unsigned short* __restrict__ memT) {
    __shared__ unsigned short T[32][516];
    const int tid = threadIdx.x;
    const int sl  = tid >> 4;
    const int c16 = tid & 15;
    const int n   = blockIdx.x * 32 + sl;
    const f32x4* row = (const f32x4*)(mem + (size_t)n * DIM);
    f32x4 v[8];
    float s = 0.f;
    #pragma unroll
    for (int j = 0; j < 8; ++j) {
        v[j] = row[c16*8 + j];
        s += v[j][0]*v[j][0] + v[j][1]*v[j][1] + v[j][2]*v[j][2] + v[j][3]*v[j][3];
    }
    #pragma unroll
    for (int off = 1; off < 16; off <<= 1) s += __shfl_xor(s, off);
    const float rn = 1.0f / fmaxf(sqrtf(s), 1e-12f);
    #pragma unroll
    for (int j = 0; j < 8; ++j) {
        us4 p, q;
        #pragma unroll
        for (int e = 0; e < 4; ++e) { p[e] = f2bf(v[j][e] * rn); q[e] = f2bf(v[j][e]); }
        *(us4*)(memN + (size_t)n * DIM + c16*32 + j*4) = p;
        *(us4*)(&T[sl][c16*32 + j*4]) = q;
    }
    __syncthreads();
    {
        const int c4 = tid & 3;
        #pragma unroll
        for (int i = 0; i < 4; ++i) {
            const int dd = i*128 + (tid >> 2);
            us8 g;
            #pragma unroll
            for (int j = 0; j < 8; ++j) g[j] = T[c4*8 + j][dd];
            *(us8*)(memT + (size_t)dd * NSLOTS + blockIdx.x*32 + c4*8) = g;
        }
    }
}

// K1: fused z-normalize + GEMM1 + exp + row sums. 1024 WGs x 512 thr (8 waves 2M x 4N).
// Tile 64r x 128s, BK=64. A held in registers (8 bf16x8/thread), staged per-phase by one
// ds_write_b128; B double-buffered via global_load_lds. 3 WGs/CU (48KB LDS).
// Writes bf16 P=exp(S) to attn-row upper halves (+4096), row sums to ws.
__global__ __launch_bounds__(512) void k1_kernel(const float* __restrict__ z,
                                                 const unsigned short* __restrict__ memN,
                                                 float* attnB,
                                                 float* __restrict__ sums) {
    __shared__ char As[2][8192];      // [64 r][64 k] bf16, row 128B, XOR-swizzled
    __shared__ char Bs[2][16384];     // [128 s][64 k] bf16, row 128B, XOR-swizzled
    __shared__ float wsums[4][64];
    const int tid  = threadIdx.x;
    const int wid  = tid >> 6;
    const int lane = tid & 63;
    const int l16  = lane & 15;
    const int l4   = lane >> 4;
    const int m    = wid >> 2, n = wid & 3;
    const size_t rowbase = (size_t)blockIdx.x * 64;
    const int r  = tid >> 3;          // this thread's A row (0..63)
    const int c8 = tid & 7;           // this thread's k-sub-slot within each 64-k window
    const int aoff = r*128 + ((c8*16) ^ ((r & 7) << 4));   // swizzled A stage dest

    // ---- phase 0: load z fp32 (coalesced, once), row-normalize, pack A-fragments ----
    us8 a[8];
    {
        const f32x4* zr = (const f32x4*)(z + (rowbase + r) * DIM);
        f32x4 va[8], vb[8];
        float s = 0.f;
        #pragma unroll
        for (int j = 0; j < 8; ++j) {
            va[j] = __builtin_nontemporal_load(zr + c8*2 + j*16);
            vb[j] = __builtin_nontemporal_load(zr + c8*2 + 1 + j*16);
            s += va[j][0]*va[j][0] + va[j][1]*va[j][1] + va[j][2]*va[j][2] + va[j][3]*va[j][3]
               + vb[j][0]*vb[j][0] + vb[j][1]*vb[j][1] + vb[j][2]*vb[j][2] + vb[j][3]*vb[j][3];
        }
        s += __shfl_xor(s, 1); s += __shfl_xor(s, 2); s += __shfl_xor(s, 4);
        const float rn = 1.0f / fmaxf(sqrtf(s), 1e-12f);
        #pragma unroll
        for (int j = 0; j < 8; ++j) {
            us8 p;
            #pragma unroll
            for (int e = 0; e < 4; ++e) { p[e] = f2bf(va[j][e] * rn); p[e + 4] = f2bf(vb[j][e] * rn); }
            a[j] = p;
        }
    }

    auto stageB = [&](int buf, int t) {
        const int c = t >> 3, ks = t & 7;
        #pragma unroll
        for (int i = 0; i < 2; ++i) {   // 16KB = 1024 x 16B
            const int f = (i*8 + wid)*64 + lane, br = f >> 3, g = f & 7;
            const char* src = (const char*)memN + (size_t)(c*128 + br) * 1024 + ks*128
                            + ((g*16) ^ ((br & 7) << 4));
            gl16(src, &Bs[buf][(i*8 + wid)*1024]);
        }
    };

    const f32x4 zeroV = {0.f, 0.f, 0.f, 0.f};
    f32x4 acc[2][2];
    #pragma unroll
    for (int mt = 0; mt < 2; ++mt)
        #pragma unroll
        for (int nt = 0; nt < 2; ++nt) acc[mt][nt] = zeroV;
    float psum[2][4];
    #pragma unroll
    for (int mt = 0; mt < 2; ++mt)
        #pragma unroll
        for (int rr = 0; rr < 4; ++rr) psum[mt][rr] = 0.f;

    *(us8*)(&As[0][aoff]) = a[0];
    stageB(0, 0);
    __syncthreads();

    for (int c = 0; c < 16; ++c) {
        #pragma unroll
        for (int ks = 0; ks < 8; ++ks) {
            const int t = c*8 + ks;
            if (t < 127) {
                *(us8*)(&As[(t + 1) & 1][aoff]) = a[(ks + 1) & 7];   // static reg index
                stageB((t + 1) & 1, t + 1);
            }
            const char* Ab = (const char*)As[t & 1];
            const char* Bb = (const char*)Bs[t & 1];
            #pragma unroll
            for (int kk = 0; kk < 2; ++kk) {
                bf16x8 af[2];
                #pragma unroll
                for (int mt = 0; mt < 2; ++mt) {
                    const int ar = m*32 + mt*16 + l16;
                    af[mt] = *(const bf16x8*)(Ab + ar*128 + ((kk*64 + l4*16) ^ ((ar & 7) << 4)));
                }
                #pragma unroll
                for (int nt = 0; nt < 2; ++nt) {
                    const int br = n*32 + nt*16 + l16;
                    bf16x8 b = *(const bf16x8*)(Bb + br*128 + ((kk*64 + l4*16) ^ ((br & 7) << 4)));
                    acc[0][nt] = __builtin_amdgcn_mfma_f32_16x16x32_bf16(af[0], b, acc[0][nt], 0, 0, 0);
                    acc[1][nt] = __builtin_amdgcn_mfma_f32_16x16x32_bf16(af[1], b, acc[1][nt], 0, 0, 0);
                }
            }
            __syncthreads();
            if (ks == 7) {
                // exp + psum + pack P chunk [64 r][128 s] bf16 into the stale B buffer
                char* Pl = (char*)Bs[t & 1];
                #pragma unroll
                for (int mt = 0; mt < 2; ++mt)
                    #pragma unroll
                    for (int nt = 0; nt < 2; ++nt)
                        #pragma unroll
                        for (int rr = 0; rr < 4; ++rr) {
                            const float e = __expf(acc[mt][nt][rr]);
                            psum[mt][rr] += e;
                            const int row = m*32 + mt*16 + l4*4 + rr;
                            const int sl  = n*32 + nt*16 + l16;
                            *(unsigned short*)(Pl + row*256 + (((sl >> 3) * 16) ^ ((row & 7) << 4)) + (sl & 7)*2) = f2bf(e);
                            acc[mt][nt][rr] = 0.f;
                        }
                __syncthreads();
                {   // bounce out: coalesced NT stores to attn upper halves
                    const int prow = tid >> 3, g8 = tid & 7;
                    char* gdst = (char*)attnB + (rowbase + prow) * 8192 + 4096 + c*256;
                    #pragma unroll
                    for (int h = 0; h < 2; ++h) {
                        us8 pv = *(const us8*)(Pl + prow*256 + (((g8 + h*8)*16) ^ ((prow & 7) << 4)));
                        __builtin_nontemporal_store(pv, (us8*)(gdst + (g8 + h*8)*16));
                    }
                }
                __syncthreads();
            }
        }
    }

    // row sums
    #pragma unroll
    for (int mt = 0; mt < 2; ++mt)
        #pragma unroll
        for (int rr = 0; rr < 4; ++rr) {
            #pragma unroll
            for (int off = 1; off < 16; off <<= 1) psum[mt][rr] += __shfl_xor(psum[mt][rr], off);
        }
    if (l16 == 0) {
        #pragma unroll
        for (int mt = 0; mt < 2; ++mt)
            #pragma unroll
            for (int rr = 0; rr < 4; ++rr)
                wsums[n][m*32 + mt*16 + l4*4 + rr] = psum[mt][rr];
    }
    __syncthreads();
    if (tid < 64) sums[rowbase + tid] = wsums[0][tid] + wsums[1][tid] + wsums[2][tid] + wsums[3][tid];
}

// K2: GEMM2 + normalized attn writes. 1024 WGs x 512 thr (8 waves 2M x 4N).
// ks outer (32 slot-chunks of 64), nb inner (4 dim-blocks of 128). 48KB LDS -> 3 WGs/CU.
__global__ __launch_bounds__(512, 4) void k2_kernel(const unsigned short* __restrict__ memT,
                                                    const float* __restrict__ sums,
                                                    float* __restrict__ zhat,
                                                    float* attnB) {
    __shared__ char ab[2][8192];      // A-tile [64 r][64 s]
    __shared__ char bb[2][16384];     // B-tile [128 d][64 s]
    __shared__ float rsums[64];
    const int tid  = threadIdx.x;
    const int wid  = tid >> 6;
    const int lane = tid & 63;
    const int l16  = lane & 15;
    const int l4   = lane >> 4;
    const int m    = wid >> 2, n = wid & 3;
    const size_t rowbase = (size_t)blockIdx.x * 64;
    const char* attnRd = (const char*)attnB;

    auto stageA = [&](int buf, int ks) {
        const int f = wid*64 + lane, ar = f >> 3, g = f & 7;
        const char* src = attnRd + (rowbase + ar) * 8192 + 4096 + ks*128
                        + ((g*16) ^ ((ar & 7) << 4));
        gl16(src, &ab[buf][0] + wid*1024);
    };
    auto stageB = [&](int buf, int ks, int nb) {
        #pragma unroll
        for (int i = 0; i < 2; ++i) {
            const int f = (i*8 + wid)*64 + lane, dr = f >> 3, g = f & 7;
            const char* src = (const char*)memT + (size_t)(nb*128 + dr) * 4096 + ks*128
                            + ((g*16) ^ ((dr & 7) << 4));
            gl16(src, &bb[buf][0] + (i*8 + wid)*1024);
        }
    };

    if (tid < 64) rsums[tid] = 1.0f / sums[rowbase + tid];

    const f32x4 zeroV = {0.f, 0.f, 0.f, 0.f};
    f32x4 acc[4][2][2];
    #pragma unroll
    for (int nb = 0; nb < 4; ++nb)
        #pragma unroll
        for (int mt = 0; mt < 2; ++mt)
            #pragma unroll
            for (int nt = 0; nt < 2; ++nt) acc[nb][mt][nt] = zeroV;

    stageA(0, 0);
    stageB(0, 0, 0);
    __syncthreads();

    for (int ks = 0; ks < 32; ++ks) {
        #pragma unroll
        for (int nb = 0; nb < 4; ++nb) {
            const int u = ks*4 + nb;
            if (nb < 3) stageB((u + 1) & 1, ks, nb + 1);
            else if (ks < 31) { stageA((ks + 1) & 1, ks + 1); stageB((u + 1) & 1, ks + 1, 0); }
            const char* Ab = (const char*)&ab[ks & 1][0];
            const char* Bb = (const char*)&bb[u & 1][0];
            if (nb == 0) {   // normalized fp32 attn write for chunk ks from staged P
                const int prow = tid >> 3;
                const int g = tid & 7;
                const float sc = rsums[prow];
                us8 pv = *(const us8*)(Ab + prow*128 + ((g*16) ^ ((prow & 7) << 4)));
                f32x4 o0, o1;
                #pragma unroll
                for (int e = 0; e < 4; ++e) { o0[e] = bf2f(pv[e]) * sc; o1[e] = bf2f(pv[e + 4]) * sc; }
                float* dst = attnB + (rowbase + prow) * NSLOTS + ks*64 + g*8;
                __builtin_nontemporal_store(o0, (f32x4*)dst);
                __builtin_nontemporal_store(o1, (f32x4*)(dst + 4));
            }
            #pragma unroll
            for (int kk = 0; kk < 2; ++kk) {
                bf16x8 af[2];
                #pragma unroll
                for (int mt = 0; mt < 2; ++mt) {
                    const int ar = m*32 + mt*16 + l16;
                    af[mt] = *(const bf16x8*)(Ab + ar*128 + ((kk*64 + l4*16) ^ ((ar & 7) << 4)));
                }
                #pragma unroll
                for (int nt = 0; nt < 2; ++nt) {
                    const int dr = n*32 + nt*16 + l16;
                    bf16x8 b = *(const bf16x8*)(Bb + dr*128 + ((kk*64 + l4*16) ^ ((dr & 7) << 4)));
                    acc[nb][0][nt] = __builtin_amdgcn_mfma_f32_16x16x32_bf16(af[0], b, acc[nb][0][nt], 0, 0, 0);
                    acc[nb][1][nt] = __builtin_amdgcn_mfma_f32_16x16x32_bf16(af[1], b, acc[nb][1][nt], 0, 0, 0);
                }
            }
            __syncthreads();
        }
    }

    // epilogue: zhat
    #pragma unroll
    for (int nb = 0; nb < 4; ++nb)
        #pragma unroll
        for (int mt = 0; mt < 2; ++mt)
            #pragma unroll
            for (int rr = 0; rr < 4; ++rr) {
                const int row = m*32 + mt*16 + l4*4 + rr;
                const float rs = rsums[row];
                float* zr = zhat + (rowbase + row) * DIM + nb*128 + n*32 + l16;
                __builtin_nontemporal_store(acc[nb][mt][0][rr] * rs, zr);
                __builtin_nontemporal_store(acc[nb][mt][1][rr] * rs, zr + 16);
            }
}

extern "C" void kernel_launch(void* const* d_in, const int* in_sizes, int n_in,
                              void* d_out, int out_size, void* d_ws, size_t ws_size,
                              hipStream_t stream) {
    const float* zin = (const float*)d_in[0];
    const float* mem = (const float*)d_in[1];
    const int B = in_sizes[0] / DIM;                       // 65536
    unsigned short* memN = (unsigned short*)d_ws;          // 2 MB
    unsigned short* memT = memN + (size_t)NSLOTS * DIM;    // 2 MB
    float* sums = (float*)(memT + (size_t)NSLOTS * DIM);   // 256 KB
    float* zhat = (float*)d_out;
    float* attn = zhat + (size_t)B * DIM;
    prep_kernel<<<NSLOTS / 32, 512, 0, stream>>>(mem, memN, memT);
    k1_kernel<<<B / 64, 512, 0, stream>>>(zin, memN, attn, sums);
    k2_kernel<<<B / 64, 512, 0, stream>>>(memT, sums, zhat, attn);
}